// Round 8
// baseline (250.849 us; speedup 1.0000x reference)
//
#include <hip/hip_runtime.h>
#include <math.h>

#define IMG    224
#define NVIEWS 6
#define BATCH  16
#define NPTS   32768
#define PLANE  (IMG * IMG)        // 50176
#define HROWS  112                // half-plane tile
#define TILE_ELEMS (HROWS * IMG)  // 25088 ints = 100352 B dynamic LDS
#define NT     1024
#define NWG    (BATCH * NVIEWS * 2)  // 192 (both kernels)
#define CAP    32768              // max entries per (b,v,half) list (provable bound)
#define NLISTS (BATCH * NVIEWS * 2)

typedef float fx4 __attribute__((ext_vector_type(4)));   // native vec for nontemporal

struct ViewTrig {
    float sa[NVIEWS], ca[NVIEWS], se[NVIEWS], ce[NVIEWS];
    float off0, off4;             // extreme splat offsets (footprint rectangle)
};

// fp32 ops with contraction OFF — these feed the pixel truncation and must
// round exactly like numpy's separate mul/add ufuncs.
__device__ __forceinline__ float fmul_(float a, float b) {
#pragma clang fp contract(off)
    return a * b;
}
__device__ __forceinline__ float fadd_(float a, float b) {
#pragma clang fp contract(off)
    return a + b;
}
__device__ __forceinline__ float fsub_(float a, float b) {
#pragma clang fp contract(off)
    return a - b;
}
// ((c + 1) * 0.5) * 223, truncate toward zero == astype(int32)
__device__ __forceinline__ int pix_(float c) {
    return (int)fmul_(fmul_(fadd_(c, 1.0f), 0.5f), 223.0f);
}

// Order-preserving float->uint map (monotone over all finite floats).
// Any real zf maps to a value > 0, so 0 is a safe "empty pixel" sentinel.
__device__ __forceinline__ unsigned fmap_(float f) {
    unsigned b = __float_as_uint(f);
    return b ^ ((unsigned)((int)b >> 31) | 0x80000000u);
}
__device__ __forceinline__ float fmap_inv_(unsigned u) {
    unsigned b = (u & 0x80000000u) ? (u ^ 0x80000000u) : ~u;
    return __uint_as_float(b);
}

__device__ __forceinline__ int lane_prefix_(unsigned long long m) {
    return __builtin_amdgcn_mbcnt_hi((unsigned)(m >> 32),
           __builtin_amdgcn_mbcnt_lo((unsigned)m, 0));
}

// ---------------------------------------------------------------------------
// Kernel 1 (prep): one scan per (b, v, point-half). Computes the strict-fp32
// clamped splat rectangle + relaxed depth payload, accumulates zmin/zmax
// partials, and wave-compacts in-bounds entries into per-(b,v,half-plane)
// lists (one atomicAdd per wave per list). Entry: {fz, cx0|cx1<<8|cy0<<16|cy1<<24}.
// A 3-row footprint can straddle the half boundary -> appended to both lists.
// ---------------------------------------------------------------------------
__global__ __launch_bounds__(NT, 4) void prep_kernel(
    const float* __restrict__ pts, unsigned* __restrict__ counters,
    uint2* __restrict__ lists, float* __restrict__ mm, ViewTrig vt)
{
    __shared__ float smin[NT / 64], smax[NT / 64];

    // XCD-aware decode: xcd = bid&7 -> batch group {xcd, xcd+8}
    const int bid  = blockIdx.x;
    const int xcd  = bid & 7;
    const int slot = bid >> 3;            // 0..23
    const int hi   = (slot >= 12) ? 1 : 0;
    const int b    = xcd + 8 * hi;
    const int vc   = slot - 12 * hi;      // 0..11
    const int v    = vc >> 1;
    const int c    = vc & 1;              // point-half
    const int bv   = b * NVIEWS + v;

    const float sa = vt.sa[v], ca = vt.ca[v], se = vt.se[v], ce = vt.ce[v];
    const float off0 = vt.off0, off4 = vt.off4;
    const float4* p4 = (const float4*)(pts + ((size_t)b * NPTS + (size_t)c * (NPTS / 2)) * 3);

    const int lane = threadIdx.x & 63;
    float zmin = INFINITY, zmax = -INFINITY;

    auto do_point = [&](float x, float y, float z) {
        // strict fp32 chain -> pixel coordinates (bit-exact vs numpy)
        const float zr = fadd_(fmul_(x, sa), fmul_(z, ca));
        const float yr = fsub_(fmul_(y, ce), fmul_(zr, se));
        const float xr = fsub_(fmul_(x, ca), fmul_(z, sa));

        const int x0i = pix_(fadd_(xr, off0));
        const int x1i = pix_(fadd_(xr, off4));
        const int y0i = pix_(fadd_(yr, off0));
        const int y1i = pix_(fadd_(yr, off4));

        // relaxed depth (feeds minmax and the splat payload)
        const float zf = fmaf(zr, ce, y * se);
        zmin = fminf(zmin, zf);
        zmax = fmaxf(zmax, zf);
        const unsigned fz = fmap_(zf);

        // clamp rect to the plane; pack as bytes (always in [0,223] after clamp)
        const int cx0 = min(max(x0i, 0), IMG - 1);
        const int cx1 = min(max(x1i, 0), IMG - 1);
        const int cy0 = min(max(y0i, 0), IMG - 1);
        const int cy1 = min(max(y1i, 0), IMG - 1);
        const unsigned pk = (unsigned)cx0 | ((unsigned)cx1 << 8) |
                            ((unsigned)cy0 << 16) | ((unsigned)cy1 << 24);

        const bool xok = (x1i >= 0) && (x0i <= IMG - 1);
        const bool h0 = xok && (y0i <= HROWS - 1) && (y1i >= 0);
        const bool h1 = xok && (y1i >= HROWS) && (y0i <= IMG - 1);

        #pragma unroll
        for (int h = 0; h < 2; ++h) {
            const bool pred = h ? h1 : h0;
            const unsigned long long m = __ballot(pred);
            if (m == 0ull) continue;                       // wave-uniform
            const int cnt = __popcll(m);
            const int leader = __builtin_ctzll(m);
            unsigned tmp = 0;
            if (lane == leader)
                tmp = atomicAdd(&counters[bv * 2 + h], (unsigned)cnt);
            const unsigned base = __shfl(tmp, leader, 64);
            if (pred)
                lists[(size_t)(bv * 2 + h) * CAP + base + lane_prefix_(m)]
                    = make_uint2(fz, pk);
        }
    };

    #pragma unroll
    for (int k = 0; k < (NPTS / 2) / (4 * NT); ++k) {   // 4 iterations
        const int g = threadIdx.x + k * NT;             // 4-point group index
        const float4 A = p4[3 * g + 0];
        const float4 B = p4[3 * g + 1];
        const float4 C = p4[3 * g + 2];
        do_point(A.x, A.y, A.z);
        do_point(A.w, B.x, B.y);
        do_point(B.z, B.w, C.x);
        do_point(C.y, C.z, C.w);
    }

    // block reduce zmin/zmax -> partials for this (bv, chunk)
    for (int o = 32; o > 0; o >>= 1) {
        zmin = fminf(zmin, __shfl_down(zmin, o, 64));
        zmax = fmaxf(zmax, __shfl_down(zmax, o, 64));
    }
    const int wave = threadIdx.x >> 6;
    if (lane == 0) { smin[wave] = zmin; smax[wave] = zmax; }
    __syncthreads();
    if (threadIdx.x == 0) {
        float mn = smin[0], mx = smax[0];
        for (int w = 1; w < NT / 64; ++w) {
            mn = fminf(mn, smin[w]);
            mx = fmaxf(mx, smax[w]);
        }
        mm[(bv * 2 + c) * 2 + 0] = mn;
        mm[(bv * 2 + c) * 2 + 1] = mx;
    }
}

// ---------------------------------------------------------------------------
// Kernel 2 (render): one WG per (b, v, half-plane). Replays its dense entry
// list into a 112x224 LDS tile with predicated 3x3 LDS atomicMax (entries
// are ~95% interior -> high lane density), then converts max-zf -> feature
// (monotone map: max(feat) == f(max(zf))) and streams to channels 0,1,2.
// ---------------------------------------------------------------------------
__global__ __launch_bounds__(NT, 4) void render_kernel(
    const unsigned* __restrict__ counters, const uint2* __restrict__ lists,
    const float* __restrict__ mm, float* __restrict__ out)
{
    extern __shared__ __align__(16) unsigned tile[];

    const int bid  = blockIdx.x;
    const int xcd  = bid & 7;
    const int slot = bid >> 3;
    const int hi   = (slot >= 12) ? 1 : 0;
    const int b    = xcd + 8 * hi;
    const int vh   = slot - 12 * hi;
    const int v    = vh >> 1;
    const int h    = vh & 1;
    const int bv   = b * NVIEWS + v;
    const int row0 = h * HROWS;

    {
        int4* t4 = (int4*)tile;
        for (int i = threadIdx.x; i < TILE_ELEMS / 4; i += NT)
            t4[i] = make_int4(0, 0, 0, 0);
    }
    __syncthreads();

    const int li = bv * 2 + h;
    const unsigned cnt = counters[li];
    const uint2* lp = lists + (size_t)li * CAP;

    for (unsigned i = threadIdx.x; i < cnt; i += NT) {
        const uint2 e = lp[i];
        const unsigned fz = e.x;
        const unsigned pk = e.y;
        const int cx0 = pk & 255;
        const int cx1 = (pk >> 8) & 255;
        const int cy0 = (pk >> 16) & 255;
        const int cy1 = pk >> 24;
        const int r0 = max(cy0, row0);
        const int r1 = min(cy1, row0 + HROWS - 1);

        #pragma unroll
        for (int dy = 0; dy < 3; ++dy) {
            const int ry = r0 + dy;
            const bool yok = (ry <= r1);
            const int base = (ry - row0) * IMG;
            #pragma unroll
            for (int dx = 0; dx < 3; ++dx) {
                const int cx = cx0 + dx;
                if (yok && (cx <= cx1)) atomicMax(&tile[base + cx], fz);
            }
        }
    }
    __syncthreads();

    // scale/bias from the two point-half partials (exact selections)
    const float zmn = fminf(mm[(bv * 2 + 0) * 2 + 0], mm[(bv * 2 + 1) * 2 + 0]);
    const float zmx = fmaxf(mm[(bv * 2 + 0) * 2 + 1], mm[(bv * 2 + 1) * 2 + 1]);
    // feat = 0.3 + 0.7*(zf-zmin)/denom == zf*scale + bias  (err ~1e-6 << 2e-2)
    const float scale = 0.7f / ((zmx - zmn) + 1e-6f);
    const float bias  = 0.3f - zmn * scale;

    float* dst = out + ((size_t)bv * 3) * PLANE + (size_t)row0 * IMG;
    const uint4* src = (const uint4*)tile;
    for (int i = threadIdx.x; i < TILE_ELEMS / 4; i += NT) {
        const uint4 u = src[i];
        fx4 f;
        f.x = (u.x == 0u) ? 0.0f : fmaf(fmap_inv_(u.x), scale, bias);
        f.y = (u.y == 0u) ? 0.0f : fmaf(fmap_inv_(u.y), scale, bias);
        f.z = (u.z == 0u) ? 0.0f : fmaf(fmap_inv_(u.z), scale, bias);
        f.w = (u.w == 0u) ? 0.0f : fmaf(fmap_inv_(u.w), scale, bias);
        #pragma unroll
        for (int c = 0; c < 3; ++c)
            __builtin_nontemporal_store(f, (fx4*)(dst + (size_t)c * PLANE) + i);
    }
}

extern "C" void kernel_launch(void* const* d_in, const int* in_sizes, int n_in,
                              void* d_out, int out_size, void* d_ws, size_t ws_size,
                              hipStream_t stream)
{
    const float* pts = (const float*)d_in[0];
    float* out = (float*)d_out;

    // workspace layout
    unsigned* counters = (unsigned*)d_ws;                                 // 192 u32
    uint2*    lists    = (uint2*)((char*)d_ws + 1024);                    // 192*32768*8 B = 48 MiB
    float*    mm       = (float*)((char*)d_ws + 1024 + (size_t)NLISTS * CAP * 8); // 384 floats

    // fp32-faithful constants (JAX x32 semantics), same as the passing rounds.
    ViewTrig vt;
    const float d2r = (float)(M_PI / 180.0);
    const float el_deg[NVIEWS] = {0.0f, 30.0f, -30.0f, 0.0f, 0.0f, 0.0f};
    for (int v = 0; v < NVIEWS; ++v) {
        float a = (float)(60 * v) * d2r;
        float e = el_deg[v] * d2r;
        vt.sa[v] = (float)sin((double)a);
        vt.ca[v] = (float)cos((double)a);
        vt.se[v] = (float)sin((double)e);
        vt.ce[v] = (float)cos((double)e);
    }
    {
        const float s = (float)(2.0 / 224.0);  // linspace end points, exact in fp32
        vt.off0 = -s;
        vt.off4 = s;
    }

    // Opt in to >64KB dynamic LDS for render (160 KiB/CU on gfx950).
    (void)hipFuncSetAttribute(reinterpret_cast<const void*>(render_kernel),
                              hipFuncAttributeMaxDynamicSharedMemorySize,
                              TILE_ELEMS * (int)sizeof(int));

    // zero the append counters (d_ws is re-poisoned before every call)
    hipMemsetAsync(counters, 0, NLISTS * sizeof(unsigned), stream);

    prep_kernel<<<NWG, NT, 0, stream>>>(pts, counters, lists, mm, vt);
    render_kernel<<<NWG, NT, TILE_ELEMS * sizeof(int), stream>>>(counters, lists, mm, out);
}

// Round 9
// 95.161 us; speedup vs baseline: 2.6361x; 2.6361x over previous
//
#include <hip/hip_runtime.h>
#include <math.h>

#define IMG    224
#define NVIEWS 6
#define BATCH  16
#define NPTS   32768
#define PLANE  (IMG * IMG)        // 50176
#define HROWS  112                // half-plane tile
#define TILE_ELEMS (HROWS * IMG)  // 25088 ints = 100352 B dynamic LDS
#define NT     1024
#define NWG    (BATCH * NVIEWS * 2)   // 192 (both kernels)
#define SEGCAP 1024               // per-(wave,list) segment capacity — provable max
#define NSEG   (BATCH * NVIEWS * 2 * 2 * 16)  // bv x h x c x wave = 6144

typedef float fx4 __attribute__((ext_vector_type(4)));   // native vec for nontemporal

struct ViewTrig {
    float sa[NVIEWS], ca[NVIEWS], se[NVIEWS], ce[NVIEWS];
    float off0, off4;             // extreme splat offsets (footprint rectangle)
};

// fp32 ops with contraction OFF — these feed the pixel truncation and must
// round exactly like numpy's separate mul/add ufuncs.
__device__ __forceinline__ float fmul_(float a, float b) {
#pragma clang fp contract(off)
    return a * b;
}
__device__ __forceinline__ float fadd_(float a, float b) {
#pragma clang fp contract(off)
    return a + b;
}
__device__ __forceinline__ float fsub_(float a, float b) {
#pragma clang fp contract(off)
    return a - b;
}
// ((c + 1) * 0.5) * 223, truncate toward zero == astype(int32)
__device__ __forceinline__ int pix_(float c) {
    return (int)fmul_(fmul_(fadd_(c, 1.0f), 0.5f), 223.0f);
}

// Order-preserving float->uint map (monotone over all finite floats).
// Any finite zf maps to a value > 0, so 0 is a safe "empty pixel" sentinel.
__device__ __forceinline__ unsigned fmap_(float f) {
    unsigned b = __float_as_uint(f);
    return b ^ ((unsigned)((int)b >> 31) | 0x80000000u);
}
__device__ __forceinline__ float fmap_inv_(unsigned u) {
    unsigned b = (u & 0x80000000u) ? (u ^ 0x80000000u) : ~u;
    return __uint_as_float(b);
}

__device__ __forceinline__ int lane_prefix_(unsigned long long m) {
    return __builtin_amdgcn_mbcnt_hi((unsigned)(m >> 32),
           __builtin_amdgcn_mbcnt_lo((unsigned)m, 0));
}

// ---------------------------------------------------------------------------
// Kernel 1 (prep): WG = (b, v, point-half c). Each wave w owns PRIVATE
// segments [bv][h][c][w] (cap 1024 = its exact point count, so overflow is
// impossible) and appends in-bounds splat entries {fz, packed rect} with
// ballot-prefix offsets — NO atomics, no cross-wave dependencies (round 8's
// returning global atomicAdd chain was the 173 us disaster). Counts are
// written unconditionally by every wave -> no memset dispatch needed.
// ---------------------------------------------------------------------------
__global__ __launch_bounds__(NT, 4) void prep_kernel(
    const float* __restrict__ pts, uint2* __restrict__ lists,
    unsigned* __restrict__ counts, float* __restrict__ mm, ViewTrig vt)
{
    __shared__ float smin[NT / 64], smax[NT / 64];

    // XCD-aware decode: xcd = bid&7 -> batches {xcd, xcd+8} stay on one XCD L2
    const int bid  = blockIdx.x;
    const int xcd  = bid & 7;
    const int slot = bid >> 3;            // 0..23
    const int hi   = (slot >= 12) ? 1 : 0;
    const int b    = xcd + 8 * hi;
    const int vc   = slot - 12 * hi;      // 0..11
    const int v    = vc >> 1;
    const int c    = vc & 1;              // point-half
    const int bv   = b * NVIEWS + v;

    const float sa = vt.sa[v], ca = vt.ca[v], se = vt.se[v], ce = vt.ce[v];
    const float off0 = vt.off0, off4 = vt.off4;
    const float4* p4 = (const float4*)(pts + ((size_t)b * NPTS + (size_t)c * (NPTS / 2)) * 3);

    const int lane = threadIdx.x & 63;
    const int wave = threadIdx.x >> 6;    // 0..15
    // segment bases for this wave's two destination lists (h = 0,1)
    uint2* seg[2];
    unsigned cnt_h[2] = {0u, 0u};
    #pragma unroll
    for (int h = 0; h < 2; ++h)
        seg[h] = lists + ((size_t)(bv * 2 + h) * 32 + (size_t)c * 16 + wave) * SEGCAP;

    float zmin = INFINITY, zmax = -INFINITY;

    auto do_point = [&](float x, float y, float z) {
        // strict fp32 chain -> pixel coordinates (bit-exact vs numpy)
        const float zr = fadd_(fmul_(x, sa), fmul_(z, ca));
        const float yr = fsub_(fmul_(y, ce), fmul_(zr, se));
        const float xr = fsub_(fmul_(x, ca), fmul_(z, sa));

        const int x0i = pix_(fadd_(xr, off0));
        const int x1i = pix_(fadd_(xr, off4));
        const int y0i = pix_(fadd_(yr, off0));
        const int y1i = pix_(fadd_(yr, off4));

        // relaxed depth (feeds minmax and the splat payload)
        const float zf = fmaf(zr, ce, y * se);
        zmin = fminf(zmin, zf);
        zmax = fmaxf(zmax, zf);
        const unsigned fz = fmap_(zf);

        // clamp rect to the plane; pack as bytes (in [0,223] after clamp)
        const int cx0 = min(max(x0i, 0), IMG - 1);
        const int cx1 = min(max(x1i, 0), IMG - 1);
        const int cy0 = min(max(y0i, 0), IMG - 1);
        const int cy1 = min(max(y1i, 0), IMG - 1);
        const unsigned pk = (unsigned)cx0 | ((unsigned)cx1 << 8) |
                            ((unsigned)cy0 << 16) | ((unsigned)cy1 << 24);

        const bool xok = (x1i >= 0) && (x0i <= IMG - 1);
        const bool p0 = xok && (y0i <= HROWS - 1) && (y1i >= 0);       // hits rows 0..111
        const bool p1 = xok && (y1i >= HROWS) && (y0i <= IMG - 1);     // hits rows 112..223

        #pragma unroll
        for (int h = 0; h < 2; ++h) {
            const bool pred = h ? p1 : p0;
            const unsigned long long m = __ballot(pred);
            if (pred)
                seg[h][cnt_h[h] + lane_prefix_(m)] = make_uint2(fz, pk);
            cnt_h[h] += (unsigned)__popcll(m);     // wave-uniform
        }
    };

    #pragma unroll
    for (int k = 0; k < (NPTS / 2) / (4 * NT); ++k) {   // 4 iterations
        const int g = threadIdx.x + k * NT;             // 4-point group index
        const float4 A = p4[3 * g + 0];
        const float4 B = p4[3 * g + 1];
        const float4 C = p4[3 * g + 2];
        do_point(A.x, A.y, A.z);
        do_point(A.w, B.x, B.y);
        do_point(B.z, B.w, C.x);
        do_point(C.y, C.z, C.w);
    }

    // store per-segment counts (every segment is covered -> no init needed)
    if (lane == 0) {
        #pragma unroll
        for (int h = 0; h < 2; ++h)
            counts[(bv * 2 + h) * 32 + c * 16 + wave] = cnt_h[h];
    }

    // block reduce zmin/zmax -> partials for this (bv, c)
    for (int o = 32; o > 0; o >>= 1) {
        zmin = fminf(zmin, __shfl_down(zmin, o, 64));
        zmax = fmaxf(zmax, __shfl_down(zmax, o, 64));
    }
    if (lane == 0) { smin[wave] = zmin; smax[wave] = zmax; }
    __syncthreads();
    if (threadIdx.x == 0) {
        float mn = smin[0], mx = smax[0];
        for (int w = 1; w < NT / 64; ++w) {
            mn = fminf(mn, smin[w]);
            mx = fmaxf(mx, smax[w]);
        }
        mm[(bv * 2 + c) * 2 + 0] = mn;
        mm[(bv * 2 + c) * 2 + 1] = mx;
    }
}

// ---------------------------------------------------------------------------
// Kernel 2 (render): WG = (b, v, plane-half h). Wave w replays segments
// {w, w+16} of its 32 (pre-filtered, ~95% in-half) into a 112x224 LDS tile
// with predicated 3x3 LDS atomicMax, then converts max-zf -> feature
// (monotone: max(feat) == f(max(zf))) and streams to channels 0,1,2.
// ---------------------------------------------------------------------------
__global__ __launch_bounds__(NT, 4) void render_kernel(
    const uint2* __restrict__ lists, const unsigned* __restrict__ counts,
    const float* __restrict__ mm, float* __restrict__ out)
{
    extern __shared__ __align__(16) unsigned tile[];

    const int bid  = blockIdx.x;
    const int xcd  = bid & 7;
    const int slot = bid >> 3;
    const int hi   = (slot >= 12) ? 1 : 0;
    const int b    = xcd + 8 * hi;
    const int vh   = slot - 12 * hi;
    const int v    = vh >> 1;
    const int h    = vh & 1;
    const int bv   = b * NVIEWS + v;
    const int row0 = h * HROWS;

    {
        int4* t4 = (int4*)tile;
        for (int i = threadIdx.x; i < TILE_ELEMS / 4; i += NT)
            t4[i] = make_int4(0, 0, 0, 0);
    }
    __syncthreads();

    const int lane = threadIdx.x & 63;
    const int wave = threadIdx.x >> 6;     // 0..15
    const int li = bv * 2 + h;

    #pragma unroll
    for (int s = 0; s < 2; ++s) {
        const int j = wave + s * 16;       // segment 0..31 within this list
        const unsigned cnt = counts[li * 32 + j];
        const uint2* lp = lists + ((size_t)li * 32 + j) * SEGCAP;

        for (unsigned i = lane; i < cnt; i += 64) {
            const uint2 e = lp[i];
            const unsigned fz = e.x;
            const unsigned pk = e.y;
            const int cx0 = pk & 255;
            const int cx1 = (pk >> 8) & 255;
            const int r0 = max((int)((pk >> 16) & 255), row0);
            const int r1 = min((int)(pk >> 24), row0 + HROWS - 1);

            #pragma unroll
            for (int dy = 0; dy < 3; ++dy) {
                const int ry = r0 + dy;
                const bool yok = (ry <= r1);
                const int base = (ry - row0) * IMG;
                #pragma unroll
                for (int dx = 0; dx < 3; ++dx) {
                    const int cx = cx0 + dx;
                    if (yok && (cx <= cx1)) atomicMax(&tile[base + cx], fz);
                }
            }
        }
    }
    __syncthreads();

    // scale/bias from the two point-half partials (exact selections)
    const float zmn = fminf(mm[(bv * 2 + 0) * 2 + 0], mm[(bv * 2 + 1) * 2 + 0]);
    const float zmx = fmaxf(mm[(bv * 2 + 0) * 2 + 1], mm[(bv * 2 + 1) * 2 + 1]);
    // feat = 0.3 + 0.7*(zf-zmin)/denom == zf*scale + bias  (err ~1e-6 << 2e-2)
    const float scale = 0.7f / ((zmx - zmn) + 1e-6f);
    const float bias  = 0.3f - zmn * scale;

    float* dst = out + ((size_t)bv * 3) * PLANE + (size_t)row0 * IMG;
    const uint4* src = (const uint4*)tile;
    for (int i = threadIdx.x; i < TILE_ELEMS / 4; i += NT) {
        const uint4 u = src[i];
        fx4 f;
        f.x = (u.x == 0u) ? 0.0f : fmaf(fmap_inv_(u.x), scale, bias);
        f.y = (u.y == 0u) ? 0.0f : fmaf(fmap_inv_(u.y), scale, bias);
        f.z = (u.z == 0u) ? 0.0f : fmaf(fmap_inv_(u.z), scale, bias);
        f.w = (u.w == 0u) ? 0.0f : fmaf(fmap_inv_(u.w), scale, bias);
        #pragma unroll
        for (int ch = 0; ch < 3; ++ch)
            __builtin_nontemporal_store(f, (fx4*)(dst + (size_t)ch * PLANE) + i);
    }
}

extern "C" void kernel_launch(void* const* d_in, const int* in_sizes, int n_in,
                              void* d_out, int out_size, void* d_ws, size_t ws_size,
                              hipStream_t stream)
{
    const float* pts = (const float*)d_in[0];
    float* out = (float*)d_out;

    // workspace layout (no init required for any of it):
    //   lists : NSEG * SEGCAP * 8 B = 48 MiB   (only counted prefixes are read)
    //   counts: NSEG u32                        (fully written by prep)
    //   mm    : 384 floats                      (fully written by prep)
    uint2*    lists  = (uint2*)d_ws;
    unsigned* counts = (unsigned*)((char*)d_ws + (size_t)NSEG * SEGCAP * 8);
    float*    mm     = (float*)((char*)counts + (size_t)NSEG * sizeof(unsigned));

    // fp32-faithful constants (JAX x32 semantics), same as the passing rounds.
    ViewTrig vt;
    const float d2r = (float)(M_PI / 180.0);
    const float el_deg[NVIEWS] = {0.0f, 30.0f, -30.0f, 0.0f, 0.0f, 0.0f};
    for (int v = 0; v < NVIEWS; ++v) {
        float a = (float)(60 * v) * d2r;
        float e = el_deg[v] * d2r;
        vt.sa[v] = (float)sin((double)a);
        vt.ca[v] = (float)cos((double)a);
        vt.se[v] = (float)sin((double)e);
        vt.ce[v] = (float)cos((double)e);
    }
    {
        const float s = (float)(2.0 / 224.0);  // linspace end points, exact in fp32
        vt.off0 = -s;
        vt.off4 = s;
    }

    // Opt in to >64KB dynamic LDS for render (160 KiB/CU on gfx950).
    (void)hipFuncSetAttribute(reinterpret_cast<const void*>(render_kernel),
                              hipFuncAttributeMaxDynamicSharedMemorySize,
                              TILE_ELEMS * (int)sizeof(int));

    prep_kernel<<<NWG, NT, 0, stream>>>(pts, lists, counts, mm, vt);
    render_kernel<<<NWG, NT, TILE_ELEMS * sizeof(int), stream>>>(lists, counts, mm, out);
}

// Round 10
// 88.086 us; speedup vs baseline: 2.8478x; 1.0803x over previous
//
#include <hip/hip_runtime.h>
#include <math.h>

#define IMG    224
#define NVIEWS 6
#define BATCH  16
#define NPTS   32768
#define PLANE  (IMG * IMG)       // 50176
#define HROWS  112               // half-plane tile
#define TILE_ELEMS (HROWS * IMG) // 25088 u32 = 100352 B dynamic LDS
#define NT     1024
#define NWAVES (NT / 64)         // 16
#define QCAP   128               // per-wave queue entries (append<64 then drain)
#define NWG    (BATCH * NVIEWS * 2) // 192

typedef float fx4 __attribute__((ext_vector_type(4)));   // native vec for nontemporal

struct ViewTrig {
    float sa[NVIEWS], ca[NVIEWS], se[NVIEWS], ce[NVIEWS];
    float off0, off4;            // extreme splat offsets (footprint rectangle)
};

// fp32 ops with contraction OFF — these feed the pixel truncation and must
// round exactly like numpy's separate mul/add ufuncs.
__device__ __forceinline__ float fmul_(float a, float b) {
#pragma clang fp contract(off)
    return a * b;
}
__device__ __forceinline__ float fadd_(float a, float b) {
#pragma clang fp contract(off)
    return a + b;
}
__device__ __forceinline__ float fsub_(float a, float b) {
#pragma clang fp contract(off)
    return a - b;
}
// ((c + 1) * 0.5) * 223, truncate toward zero == astype(int32)
__device__ __forceinline__ int pix_(float c) {
    return (int)fmul_(fmul_(fadd_(c, 1.0f), 0.5f), 223.0f);
}

// Order-preserving float->uint map (monotone over all finite floats).
// Any finite zf maps to a value > 0, so 0 is a safe "empty pixel" sentinel.
__device__ __forceinline__ unsigned fmap_(float f) {
    unsigned b = __float_as_uint(f);
    return b ^ ((unsigned)((int)b >> 31) | 0x80000000u);
}
__device__ __forceinline__ float fmap_inv_(unsigned u) {
    unsigned b = (u & 0x80000000u) ? (u ^ 0x80000000u) : ~u;
    return __uint_as_float(b);
}

__device__ __forceinline__ int lane_prefix_(unsigned long long m) {
    return __builtin_amdgcn_mbcnt_hi((unsigned)(m >> 32),
           __builtin_amdgcn_mbcnt_lo((unsigned)m, 0));
}

// ---------------------------------------------------------------------------
// Fused single-scan render with WAVE-PRIVATE LDS QUEUE compaction.
// One 1024-thread WG per (b, v, half-plane).
//
// Only ~23% of (point, half) passes hit the tile, but predicated atomics
// ISSUE on the LDS pipe regardless (9 issues/point) — the measured scan
// bottleneck. Fix: each wave ballot-compacts its hits into a private
// 128-entry LDS queue (no atomics, no barriers; wave-internal RAW through
// the in-order LDS pipe) and drains 64 at a time at ~100% lane density.
// LDS issues/point: ~9 -> ~3.
//
// Monotonicity: feat = zf*scale+bias, scale>0 -> max(feat) = f(max(zf));
// splat fmap(zf), convert in the epilogue. Strict-fp32 pixel chain is
// bit-exact vs numpy; zf/feat value is relaxed (tolerance 2e-2).
// ---------------------------------------------------------------------------
__global__ __launch_bounds__(NT, 4) void render_kernel(
    const float* __restrict__ pts, float* __restrict__ out, ViewTrig vt)
{
    extern __shared__ __align__(16) unsigned tile[];
    __shared__ uint2 wq[NWAVES][QCAP];              // 16 KB static
    __shared__ float smin[NWAVES], smax[NWAVES];

    // XCD-aware decode: xcd = bid&7 -> batches {xcd, xcd+8} pin to one XCD L2
    const int bid  = blockIdx.x;
    const int xcd  = bid & 7;
    const int slot = bid >> 3;            // 0..23
    const int hi   = (slot >= 12) ? 1 : 0;
    const int b    = xcd + 8 * hi;
    const int vh   = slot - 12 * hi;
    const int v    = vh >> 1;
    const int h    = vh & 1;
    const int bv   = b * NVIEWS + v;
    const int row0 = h * HROWS;
    const int row1 = row0 + HROWS - 1;

    const float sa = vt.sa[v], ca = vt.ca[v], se = vt.se[v], ce = vt.ce[v];
    const float off0 = vt.off0, off4 = vt.off4;
    const float4* p4 = (const float4*)(pts + (size_t)b * NPTS * 3);

    const int lane = threadIdx.x & 63;
    const int wave = threadIdx.x >> 6;

    // zero tile (b128 stores)
    {
        int4* t4 = (int4*)tile;
        for (int i = threadIdx.x; i < TILE_ELEMS / 4; i += NT)
            t4[i] = make_int4(0, 0, 0, 0);
    }
    __syncthreads();

    float zmin = INFINITY, zmax = -INFINITY;
    unsigned qcnt = 0;                    // wave-uniform queue fill

    // dense drain of 64 queue entries (all lanes useful)
    auto drain64 = [&]() {
        qcnt -= 64;
        const uint2 e = wq[wave][qcnt + lane];
        const unsigned fz = e.x, pk = e.y;
        const int cx0 = pk & 255;
        const int cx1 = (pk >> 8) & 255;
        const int r0 = max((int)((pk >> 16) & 255), row0) - row0;
        const int r1 = min((int)(pk >> 24), row1) - row0;
        #pragma unroll
        for (int dy = 0; dy < 3; ++dy) {
            const int ry = r0 + dy;
            const bool yok = (ry <= r1);
            #pragma unroll
            for (int dx = 0; dx < 3; ++dx) {
                const int cx = cx0 + dx;
                if (yok && (cx <= cx1)) atomicMax(&tile[ry * IMG + cx], fz);
            }
        }
    };

    auto do_point = [&](float x, float y, float z) {
        // strict fp32 chain -> pixel coordinates (bit-exact vs numpy)
        const float zr = fadd_(fmul_(x, sa), fmul_(z, ca));
        const float yr = fsub_(fmul_(y, ce), fmul_(zr, se));
        const float xr = fsub_(fmul_(x, ca), fmul_(z, sa));

        const int x0i = pix_(fadd_(xr, off0));
        const int x1i = pix_(fadd_(xr, off4));
        const int y0i = pix_(fadd_(yr, off0));
        const int y1i = pix_(fadd_(yr, off4));

        // relaxed depth (feeds minmax and the splat payload)
        const float zf = fmaf(zr, ce, y * se);
        zmin = fminf(zmin, zf);
        zmax = fmaxf(zmax, zf);

        const bool pred = (x1i >= 0) && (x0i <= IMG - 1) &&
                          (y1i >= row0) && (y0i <= row1);
        const unsigned long long m = __ballot(pred);
        if (pred) {
            const int cx0 = min(max(x0i, 0), IMG - 1);
            const int cx1 = min(max(x1i, 0), IMG - 1);
            const int cy0 = min(max(y0i, 0), IMG - 1);
            const int cy1 = min(max(y1i, 0), IMG - 1);
            const unsigned pk = (unsigned)cx0 | ((unsigned)cx1 << 8) |
                                ((unsigned)cy0 << 16) | ((unsigned)cy1 << 24);
            wq[wave][qcnt + lane_prefix_(m)] = make_uint2(fmap_(zf), pk);
        }
        qcnt += (unsigned)__popcll(m);    // wave-uniform
        if (qcnt >= 64) drain64();        // keeps qcnt < 64 (append adds <= 64)
    };

    #pragma unroll
    for (int k = 0; k < NPTS / (4 * NT); ++k) {   // 8 iterations
        const int g = threadIdx.x + k * NT;       // 4-point group index
        const float4 A = p4[3 * g + 0];
        const float4 B = p4[3 * g + 1];
        const float4 C = p4[3 * g + 2];
        do_point(A.x, A.y, A.z);
        do_point(A.w, B.x, B.y);
        do_point(B.z, B.w, C.x);
        do_point(C.y, C.z, C.w);
    }

    // final partial drain (< 64 entries)
    if (lane < (int)qcnt) {
        const uint2 e = wq[wave][lane];
        const unsigned fz = e.x, pk = e.y;
        const int cx0 = pk & 255;
        const int cx1 = (pk >> 8) & 255;
        const int r0 = max((int)((pk >> 16) & 255), row0) - row0;
        const int r1 = min((int)(pk >> 24), row1) - row0;
        #pragma unroll
        for (int dy = 0; dy < 3; ++dy) {
            const int ry = r0 + dy;
            const bool yok = (ry <= r1);
            #pragma unroll
            for (int dx = 0; dx < 3; ++dx) {
                const int cx = cx0 + dx;
                if (yok && (cx <= cx1)) atomicMax(&tile[ry * IMG + cx], fz);
            }
        }
    }

    // ---- block reduce zmin/zmax ----
    for (int o = 32; o > 0; o >>= 1) {
        zmin = fminf(zmin, __shfl_down(zmin, o, 64));
        zmax = fmaxf(zmax, __shfl_down(zmax, o, 64));
    }
    if (lane == 0) { smin[wave] = zmin; smax[wave] = zmax; }
    __syncthreads();   // also orders all LDS atomics before the epilogue
    if (threadIdx.x == 0) {
        float mn = smin[0], mx = smax[0];
        for (int w = 1; w < NWAVES; ++w) {
            mn = fminf(mn, smin[w]);
            mx = fmaxf(mx, smax[w]);
        }
        smin[0] = mn; smax[0] = mx;
    }
    __syncthreads();
    // feat = 0.3 + 0.7*(zf-zmin)/denom == zf*scale + bias  (err ~1e-6 << 2e-2)
    const float scale = 0.7f / ((smax[0] - smin[0]) + 1e-6f);
    const float bias  = 0.3f - smin[0] * scale;

    // ---- epilogue: tile -> feat -> channels 0,1,2 (non-temporal fx4) ----
    float* dst = out + ((size_t)bv * 3) * PLANE + (size_t)row0 * IMG;
    const uint4* src = (const uint4*)tile;
    for (int i = threadIdx.x; i < TILE_ELEMS / 4; i += NT) {
        const uint4 u = src[i];
        fx4 f;
        f.x = (u.x == 0u) ? 0.0f : fmaf(fmap_inv_(u.x), scale, bias);
        f.y = (u.y == 0u) ? 0.0f : fmaf(fmap_inv_(u.y), scale, bias);
        f.z = (u.z == 0u) ? 0.0f : fmaf(fmap_inv_(u.z), scale, bias);
        f.w = (u.w == 0u) ? 0.0f : fmaf(fmap_inv_(u.w), scale, bias);
        #pragma unroll
        for (int c = 0; c < 3; ++c)
            __builtin_nontemporal_store(f, (fx4*)(dst + (size_t)c * PLANE) + i);
    }
}

extern "C" void kernel_launch(void* const* d_in, const int* in_sizes, int n_in,
                              void* d_out, int out_size, void* d_ws, size_t ws_size,
                              hipStream_t stream)
{
    const float* pts = (const float*)d_in[0];
    float* out = (float*)d_out;

    // fp32-faithful constants (JAX x32 semantics), same as the passing rounds.
    ViewTrig vt;
    const float d2r = (float)(M_PI / 180.0);
    const float el_deg[NVIEWS] = {0.0f, 30.0f, -30.0f, 0.0f, 0.0f, 0.0f};
    for (int v = 0; v < NVIEWS; ++v) {
        float a = (float)(60 * v) * d2r;
        float e = el_deg[v] * d2r;
        vt.sa[v] = (float)sin((double)a);
        vt.ca[v] = (float)cos((double)a);
        vt.se[v] = (float)sin((double)e);
        vt.ce[v] = (float)cos((double)e);
    }
    {
        const float s = (float)(2.0 / 224.0);  // linspace end points, exact in fp32
        vt.off0 = -s;
        vt.off4 = s;
    }

    // Opt in to >64KB dynamic LDS (160 KiB/CU on gfx950). Graph-capture safe.
    (void)hipFuncSetAttribute(reinterpret_cast<const void*>(render_kernel),
                              hipFuncAttributeMaxDynamicSharedMemorySize,
                              TILE_ELEMS * (int)sizeof(int));

    render_kernel<<<NWG, NT, TILE_ELEMS * sizeof(int), stream>>>(pts, out, vt);
}